// Round 1
// baseline (2503.340 us; speedup 1.0000x reference)
//
#include <hip/hip_runtime.h>

#define NND 100000
#define NE  1600000
#define NF  512
#define NH  64
#define NC  40

// ---------------- GEMM1: support1[N,64] = x[N,512] @ W1[512,64] ----------------
// 64x64 output tile per block, K-step 64. 256 threads = 16x16, 4x4 micro-tile.
__global__ __launch_bounds__(256) void gemm1_k(const float* __restrict__ x,
                                               const float* __restrict__ W,
                                               float* __restrict__ out) {
  __shared__ float xs[64][68];   // [row][k], pad->stride 68 keeps float4 align, spreads banks
  __shared__ float ws[64][68];   // [k][col]
  const int t  = threadIdx.x;
  const int tx = t & 15, ty = t >> 4;
  const int rowBase = blockIdx.x * 64;
  float acc[4][4] = {};

  for (int k0 = 0; k0 < NF; k0 += 64) {
    // load x tile: 64 rows x 64 k = 1024 float4, 4 per thread (coalesced along k)
#pragma unroll
    for (int i = 0; i < 4; ++i) {
      int flat = t + i * 256;          // float4 index
      int r = flat >> 4, q = flat & 15;
      int row = rowBase + r;
      float4 v = make_float4(0.f, 0.f, 0.f, 0.f);
      if (row < NND) v = *(const float4*)(x + (size_t)row * NF + k0 + q * 4);
      *(float4*)&xs[r][q * 4] = v;
    }
    // load W tile: 64 k x 64 cols
#pragma unroll
    for (int i = 0; i < 4; ++i) {
      int flat = t + i * 256;
      int kk = flat >> 4, q = flat & 15;
      float4 v = *(const float4*)(W + (size_t)(k0 + kk) * NH + q * 4);
      *(float4*)&ws[kk][q * 4] = v;
    }
    __syncthreads();
#pragma unroll 8
    for (int kk = 0; kk < 64; ++kk) {
      float a0 = xs[ty * 4 + 0][kk];
      float a1 = xs[ty * 4 + 1][kk];
      float a2 = xs[ty * 4 + 2][kk];
      float a3 = xs[ty * 4 + 3][kk];
      float4 b = *(const float4*)&ws[kk][tx * 4];
      acc[0][0] += a0 * b.x; acc[0][1] += a0 * b.y; acc[0][2] += a0 * b.z; acc[0][3] += a0 * b.w;
      acc[1][0] += a1 * b.x; acc[1][1] += a1 * b.y; acc[1][2] += a1 * b.z; acc[1][3] += a1 * b.w;
      acc[2][0] += a2 * b.x; acc[2][1] += a2 * b.y; acc[2][2] += a2 * b.z; acc[2][3] += a2 * b.w;
      acc[3][0] += a3 * b.x; acc[3][1] += a3 * b.y; acc[3][2] += a3 * b.z; acc[3][3] += a3 * b.w;
    }
    __syncthreads();
  }
#pragma unroll
  for (int i = 0; i < 4; ++i) {
    int row = rowBase + ty * 4 + i;
    if (row < NND)
      *(float4*)(out + (size_t)row * NH + tx * 4) =
          make_float4(acc[i][0], acc[i][1], acc[i][2], acc[i][3]);
  }
}

// ---------------- SpMM over 64 features: out[row] += val * feat[col] ----------------
// 16 threads per edge, one float4 each.
__global__ __launch_bounds__(256) void spmm1_k(const float* __restrict__ vals,
                                               const int* __restrict__ rows,
                                               const int* __restrict__ cols,
                                               const float* __restrict__ feat,
                                               float* __restrict__ out) {
  int idx = blockIdx.x * 256 + threadIdx.x;
  int e = idx >> 4;
  if (e >= NE) return;
  int q = idx & 15;
  float v = vals[e];
  int c = cols[e], r = rows[e];
  float4 s = *(const float4*)(feat + (size_t)c * NH + q * 4);
  float* o = out + (size_t)r * NH + q * 4;
  atomicAdd(o + 0, v * s.x);
  atomicAdd(o + 1, v * s.y);
  atomicAdd(o + 2, v * s.z);
  atomicAdd(o + 3, v * s.w);
}

// ---------------- GEMM2: support2[N,40] = relu(h+b1) @ W10[64,40] ----------------
// 64 threads per block, 64 rows per block, one row per thread.
__global__ __launch_bounds__(64) void gemm2_k(const float* __restrict__ h,
                                              const float* __restrict__ b1,
                                              const float* __restrict__ W10,
                                              float* __restrict__ out) {
  __shared__ float hs[64][65];
  __shared__ float wl[64][44];   // stride 44 -> float4-aligned rows
  const int t = threadIdx.x;
  const int rowBase = blockIdx.x * 64;
  // stage relu(h+b1) tile: 1024 float4, 16 per thread (coalesced)
#pragma unroll
  for (int i = 0; i < 16; ++i) {
    int flat = t + i * 64;           // float4 index
    int r = flat >> 4, q = flat & 15;
    int row = rowBase + r;
    float4 v = make_float4(0.f, 0.f, 0.f, 0.f);
    if (row < NND) {
      v = *(const float4*)(h + (size_t)row * NH + q * 4);
      float4 b = *(const float4*)(b1 + q * 4);
      v.x = fmaxf(v.x + b.x, 0.f);
      v.y = fmaxf(v.y + b.y, 0.f);
      v.z = fmaxf(v.z + b.z, 0.f);
      v.w = fmaxf(v.w + b.w, 0.f);
    }
    hs[r][q * 4 + 0] = v.x;
    hs[r][q * 4 + 1] = v.y;
    hs[r][q * 4 + 2] = v.z;
    hs[r][q * 4 + 3] = v.w;
  }
  // stage W10: 64x40 = 640 float4, 10 per thread
#pragma unroll
  for (int i = 0; i < 10; ++i) {
    int flat = t + i * 64;           // float4 index; flat = k*10 + c4
    int k = flat / 10, c4 = flat - k * 10;
    float4 v = *(const float4*)(W10 + (size_t)flat * 4);
    *(float4*)&wl[k][c4 * 4] = v;
  }
  __syncthreads();

  float4 acc[10] = {};
#pragma unroll 8
  for (int k = 0; k < 64; ++k) {
    float a = hs[t][k];
#pragma unroll
    for (int c = 0; c < 10; ++c) {
      float4 w = *(const float4*)&wl[k][c * 4];
      acc[c].x += a * w.x;
      acc[c].y += a * w.y;
      acc[c].z += a * w.z;
      acc[c].w += a * w.w;
    }
  }
  int row = rowBase + t;
  if (row < NND) {
#pragma unroll
    for (int c = 0; c < 10; ++c)
      *(float4*)(out + (size_t)row * NC + c * 4) = acc[c];
  }
}

// ---------------- SpMM over 40 features ----------------
// 10 threads per edge, one float4 each.
__global__ __launch_bounds__(256) void spmm2_k(const float* __restrict__ vals,
                                               const int* __restrict__ rows,
                                               const int* __restrict__ cols,
                                               const float* __restrict__ feat,
                                               float* __restrict__ out) {
  int idx = blockIdx.x * 256 + threadIdx.x;
  int e = idx / 10;
  if (e >= NE) return;
  int q = idx - e * 10;
  float v = vals[e];
  int c = cols[e], r = rows[e];
  float4 s = *(const float4*)(feat + (size_t)c * NC + q * 4);
  float* o = out + (size_t)r * NC + q * 4;
  atomicAdd(o + 0, v * s.x);
  atomicAdd(o + 1, v * s.y);
  atomicAdd(o + 2, v * s.z);
  atomicAdd(o + 3, v * s.w);
}

// ---------------- bias + log_softmax, in-place on d_out ----------------
__global__ __launch_bounds__(256) void lsm_k(float* __restrict__ out,
                                             const float* __restrict__ b10) {
  int row = blockIdx.x * 256 + threadIdx.x;
  if (row >= NND) return;
  float v[NC];
  float* p = out + (size_t)row * NC;
#pragma unroll
  for (int c = 0; c < 10; ++c) {
    float4 t4 = *(const float4*)(p + c * 4);
    float4 b4 = *(const float4*)(b10 + c * 4);
    v[c * 4 + 0] = t4.x + b4.x;
    v[c * 4 + 1] = t4.y + b4.y;
    v[c * 4 + 2] = t4.z + b4.z;
    v[c * 4 + 3] = t4.w + b4.w;
  }
  float m = v[0];
#pragma unroll
  for (int i = 1; i < NC; ++i) m = fmaxf(m, v[i]);
  float s = 0.f;
#pragma unroll
  for (int i = 0; i < NC; ++i) s += __expf(v[i] - m);
  float l = __logf(s);
#pragma unroll
  for (int c = 0; c < 10; ++c) {
    float4 o4 = make_float4(v[c * 4 + 0] - m - l, v[c * 4 + 1] - m - l,
                            v[c * 4 + 2] - m - l, v[c * 4 + 3] - m - l);
    *(float4*)(p + c * 4) = o4;
  }
}

extern "C" void kernel_launch(void* const* d_in, const int* in_sizes, int n_in,
                              void* d_out, int out_size, void* d_ws, size_t ws_size,
                              hipStream_t stream) {
  const float* x    = (const float*)d_in[0];
  const float* adj  = (const float*)d_in[1];
  const float* W1   = (const float*)d_in[2];
  const float* b1   = (const float*)d_in[3];
  const float* W10  = (const float*)d_in[4];
  const float* b10  = (const float*)d_in[5];
  const int*   erow = (const int*)d_in[6];
  const int*   ecol = (const int*)d_in[7];
  float* out = (float*)d_out;

  float* bufA = (float*)d_ws;                  // support1 [N,64]; later support2 [N,40]
  float* bufB = bufA + (size_t)NND * NH;       // h [N,64]

  gemm1_k<<<(NND + 63) / 64, 256, 0, stream>>>(x, W1, bufA);
  hipMemsetAsync(bufB, 0, (size_t)NND * NH * sizeof(float), stream);
  spmm1_k<<<(NE * 16) / 256, 256, 0, stream>>>(adj, erow, ecol, bufA, bufB);
  gemm2_k<<<(NND + 63) / 64, 64, 0, stream>>>(bufB, b1, W10, bufA);
  hipMemsetAsync(out, 0, (size_t)NND * NC * sizeof(float), stream);
  spmm2_k<<<(NE * 10) / 256, 256, 0, stream>>>(adj, erow, ecol, bufA, out);
  lsm_k<<<(NND + 255) / 256, 256, 0, stream>>>(out, b10);
}

// Round 2
// 764.221 us; speedup vs baseline: 3.2757x; 3.2757x over previous
//
#include <hip/hip_runtime.h>

#define NND 100000
#define NE  1600000
#define NF  512
#define NH  64
#define NC  40

// ---------------- GEMM1: support1[N,64] = x[N,512] @ W1[512,64] ----------------
__global__ __launch_bounds__(256) void gemm1_k(const float* __restrict__ x,
                                               const float* __restrict__ W,
                                               float* __restrict__ out) {
  __shared__ float xs[64][68];
  __shared__ float ws[64][68];
  const int t  = threadIdx.x;
  const int tx = t & 15, ty = t >> 4;
  const int rowBase = blockIdx.x * 64;
  float acc[4][4] = {};

  for (int k0 = 0; k0 < NF; k0 += 64) {
#pragma unroll
    for (int i = 0; i < 4; ++i) {
      int flat = t + i * 256;
      int r = flat >> 4, q = flat & 15;
      int row = rowBase + r;
      float4 v = make_float4(0.f, 0.f, 0.f, 0.f);
      if (row < NND) v = *(const float4*)(x + (size_t)row * NF + k0 + q * 4);
      *(float4*)&xs[r][q * 4] = v;
    }
#pragma unroll
    for (int i = 0; i < 4; ++i) {
      int flat = t + i * 256;
      int kk = flat >> 4, q = flat & 15;
      float4 v = *(const float4*)(W + (size_t)(k0 + kk) * NH + q * 4);
      *(float4*)&ws[kk][q * 4] = v;
    }
    __syncthreads();
#pragma unroll 8
    for (int kk = 0; kk < 64; ++kk) {
      float a0 = xs[ty * 4 + 0][kk];
      float a1 = xs[ty * 4 + 1][kk];
      float a2 = xs[ty * 4 + 2][kk];
      float a3 = xs[ty * 4 + 3][kk];
      float4 b = *(const float4*)&ws[kk][tx * 4];
      acc[0][0] += a0 * b.x; acc[0][1] += a0 * b.y; acc[0][2] += a0 * b.z; acc[0][3] += a0 * b.w;
      acc[1][0] += a1 * b.x; acc[1][1] += a1 * b.y; acc[1][2] += a1 * b.z; acc[1][3] += a1 * b.w;
      acc[2][0] += a2 * b.x; acc[2][1] += a2 * b.y; acc[2][2] += a2 * b.z; acc[2][3] += a2 * b.w;
      acc[3][0] += a3 * b.x; acc[3][1] += a3 * b.y; acc[3][2] += a3 * b.z; acc[3][3] += a3 * b.w;
    }
    __syncthreads();
  }
#pragma unroll
  for (int i = 0; i < 4; ++i) {
    int row = rowBase + ty * 4 + i;
    if (row < NND)
      *(float4*)(out + (size_t)row * NH + tx * 4) =
          make_float4(acc[i][0], acc[i][1], acc[i][2], acc[i][3]);
  }
}

// ---------------- CSR build ----------------
__global__ __launch_bounds__(256) void hist_k(const int* __restrict__ rows,
                                              int* __restrict__ cnt) {
  int i = blockIdx.x * 256 + threadIdx.x;
  if (i < NE) atomicAdd(&cnt[rows[i]], 1);
}

// single block, 1024 threads: exclusive scan of cnt -> rowptr; cursor=start (in place over cnt)
__global__ __launch_bounds__(1024) void scan_k(int* __restrict__ cnt_cursor,
                                               int* __restrict__ rowptr) {
  __shared__ int part[1024];
  const int t = threadIdx.x;
  const int CH = (NND + 1023) / 1024;   // 98
  const int base = t * CH;
  int s = 0;
  for (int i = 0; i < CH; ++i) {
    int idx = base + i;
    if (idx < NND) s += cnt_cursor[idx];
  }
  part[t] = s;
  __syncthreads();
  for (int off = 1; off < 1024; off <<= 1) {
    int v = (t >= off) ? part[t - off] : 0;
    __syncthreads();
    part[t] += v;
    __syncthreads();
  }
  int run = (t == 0) ? 0 : part[t - 1];
  for (int i = 0; i < CH; ++i) {
    int idx = base + i;
    if (idx < NND) {
      int c = cnt_cursor[idx];
      rowptr[idx] = run;
      cnt_cursor[idx] = run;   // becomes the scatter cursor
      run += c;
    }
  }
  if (t == 0) rowptr[NND] = NE;
}

__global__ __launch_bounds__(256) void scatter_k(const float* __restrict__ vals,
                                                 const int* __restrict__ rows,
                                                 const int* __restrict__ cols,
                                                 int* __restrict__ cursor,
                                                 int* __restrict__ col_s,
                                                 float* __restrict__ val_s) {
  int i = blockIdx.x * 256 + threadIdx.x;
  if (i >= NE) return;
  int r = rows[i];
  int pos = atomicAdd(&cursor[r], 1);
  col_s[pos] = cols[i];
  val_s[pos] = vals[i];
}

// ---------------- SpMM1 gather: h[r] = relu(sum val*feat[col] + b1), wave per row ----------------
__global__ __launch_bounds__(256) void spmm1g_k(const int* __restrict__ rowptr,
                                                const int* __restrict__ col_s,
                                                const float* __restrict__ val_s,
                                                const float* __restrict__ feat,
                                                const float* __restrict__ b1,
                                                float* __restrict__ h) {
  int wid = threadIdx.x >> 6, lane = threadIdx.x & 63;
  int r = blockIdx.x * 4 + wid;
  if (r >= NND) return;
  int beg = rowptr[r], end = rowptr[r + 1];
  float acc0 = 0.f, acc1 = 0.f;
  int i = beg;
  for (; i + 1 < end; i += 2) {
    acc0 += val_s[i]     * feat[(size_t)col_s[i]     * NH + lane];
    acc1 += val_s[i + 1] * feat[(size_t)col_s[i + 1] * NH + lane];
  }
  if (i < end) acc0 += val_s[i] * feat[(size_t)col_s[i] * NH + lane];
  h[(size_t)r * NH + lane] = fmaxf(acc0 + acc1 + b1[lane], 0.f);
}

// ---------------- GEMM2: support2[N,40] = h[N,64] @ W10[64,40] ----------------
__global__ __launch_bounds__(64) void gemm2_k(const float* __restrict__ h,
                                              const float* __restrict__ W10,
                                              float* __restrict__ out) {
  __shared__ float hs[64][65];
  __shared__ float wl[64][44];
  const int t = threadIdx.x;
  const int rowBase = blockIdx.x * 64;
#pragma unroll
  for (int i = 0; i < 16; ++i) {
    int flat = t + i * 64;
    int r = flat >> 4, q = flat & 15;
    int row = rowBase + r;
    float4 v = make_float4(0.f, 0.f, 0.f, 0.f);
    if (row < NND) v = *(const float4*)(h + (size_t)row * NH + q * 4);
    hs[r][q * 4 + 0] = v.x;
    hs[r][q * 4 + 1] = v.y;
    hs[r][q * 4 + 2] = v.z;
    hs[r][q * 4 + 3] = v.w;
  }
#pragma unroll
  for (int i = 0; i < 10; ++i) {
    int flat = t + i * 64;
    int k = flat / 10, c4 = flat - k * 10;
    float4 v = *(const float4*)(W10 + (size_t)flat * 4);
    *(float4*)&wl[k][c4 * 4] = v;
  }
  __syncthreads();

  float4 acc[10] = {};
#pragma unroll 8
  for (int k = 0; k < 64; ++k) {
    float a = hs[t][k];
#pragma unroll
    for (int c = 0; c < 10; ++c) {
      float4 w = *(const float4*)&wl[k][c * 4];
      acc[c].x += a * w.x;
      acc[c].y += a * w.y;
      acc[c].z += a * w.z;
      acc[c].w += a * w.w;
    }
  }
  int row = rowBase + t;
  if (row < NND) {
#pragma unroll
    for (int c = 0; c < 10; ++c)
      *(float4*)(out + (size_t)row * NC + c * 4) = acc[c];
  }
}

// ---------------- SpMM2 gather + b10 + log_softmax fused, wave per row ----------------
__global__ __launch_bounds__(256) void spmm2g_k(const int* __restrict__ rowptr,
                                                const int* __restrict__ col_s,
                                                const float* __restrict__ val_s,
                                                const float* __restrict__ s2,
                                                const float* __restrict__ b10,
                                                float* __restrict__ out) {
  int wid = threadIdx.x >> 6, lane = threadIdx.x & 63;
  int r = blockIdx.x * 4 + wid;
  if (r >= NND) return;
  int beg = rowptr[r], end = rowptr[r + 1];
  float acc0 = 0.f, acc1 = 0.f;
  if (lane < NC) {
    int i = beg;
    for (; i + 1 < end; i += 2) {
      acc0 += val_s[i]     * s2[(size_t)col_s[i]     * NC + lane];
      acc1 += val_s[i + 1] * s2[(size_t)col_s[i + 1] * NC + lane];
    }
    if (i < end) acc0 += val_s[i] * s2[(size_t)col_s[i] * NC + lane];
  }
  float vv = (lane < NC) ? acc0 + acc1 + b10[lane] : -INFINITY;
  float m = vv;
#pragma unroll
  for (int off = 32; off; off >>= 1) m = fmaxf(m, __shfl_xor(m, off, 64));
  float e = (lane < NC) ? __expf(vv - m) : 0.f;
  float s = e;
#pragma unroll
  for (int off = 32; off; off >>= 1) s += __shfl_xor(s, off, 64);
  if (lane < NC) out[(size_t)r * NC + lane] = vv - m - __logf(s);
}

extern "C" void kernel_launch(void* const* d_in, const int* in_sizes, int n_in,
                              void* d_out, int out_size, void* d_ws, size_t ws_size,
                              hipStream_t stream) {
  const float* x    = (const float*)d_in[0];
  const float* adj  = (const float*)d_in[1];
  const float* W1   = (const float*)d_in[2];
  const float* b1   = (const float*)d_in[3];
  const float* W10  = (const float*)d_in[4];
  const float* b10  = (const float*)d_in[5];
  const int*   erow = (const int*)d_in[6];
  const int*   ecol = (const int*)d_in[7];
  float* out = (float*)d_out;

  float* bufA   = (float*)d_ws;                      // support1 [N,64]; later support2 [N,40]
  float* h      = bufA + (size_t)NND * NH;           // [N,64]
  int*   rowptr = (int*)(h + (size_t)NND * NH);      // [N+1]
  int*   cursor = rowptr + (NND + 1);                // [N] counts -> cursors
  int*   col_s  = cursor + NND;                      // [E]
  float* val_s  = (float*)(col_s + NE);              // [E]

  // CSR build (overlapped-ish with gemm1 in issue order; stream-serial anyway)
  hipMemsetAsync(cursor, 0, (size_t)NND * sizeof(int), stream);
  hist_k<<<(NE + 255) / 256, 256, 0, stream>>>(erow, cursor);
  scan_k<<<1, 1024, 0, stream>>>(cursor, rowptr);
  scatter_k<<<(NE + 255) / 256, 256, 0, stream>>>(adj, erow, ecol, cursor, col_s, val_s);

  gemm1_k<<<(NND + 63) / 64, 256, 0, stream>>>(x, W1, bufA);
  spmm1g_k<<<(NND + 3) / 4, 256, 0, stream>>>(rowptr, col_s, val_s, bufA, b1, h);
  gemm2_k<<<(NND + 63) / 64, 64, 0, stream>>>(h, W10, bufA);
  spmm2g_k<<<(NND + 3) / 4, 256, 0, stream>>>(rowptr, col_s, val_s, bufA, b10, out);
}

// Round 3
// 515.103 us; speedup vs baseline: 4.8599x; 1.4836x over previous
//
#include <hip/hip_runtime.h>

#define NND 100000
#define NE  1600000
#define NF  512
#define NH  64
#define NC  40

#define SCAN_CH 1024
#define NSB ((NND + SCAN_CH - 1) / SCAN_CH)   // 98 blocks

// ---------------- GEMM1: support1[N,64] = x[N,512] @ W1[512,64] ----------------
__global__ __launch_bounds__(256) void gemm1_k(const float* __restrict__ x,
                                               const float* __restrict__ W,
                                               float* __restrict__ out) {
  __shared__ float xs[64][68];
  __shared__ float ws[64][68];
  const int t  = threadIdx.x;
  const int tx = t & 15, ty = t >> 4;
  const int rowBase = blockIdx.x * 64;
  float acc[4][4] = {};

  for (int k0 = 0; k0 < NF; k0 += 64) {
#pragma unroll
    for (int i = 0; i < 4; ++i) {
      int flat = t + i * 256;
      int r = flat >> 4, q = flat & 15;
      int row = rowBase + r;
      float4 v = make_float4(0.f, 0.f, 0.f, 0.f);
      if (row < NND) v = *(const float4*)(x + (size_t)row * NF + k0 + q * 4);
      *(float4*)&xs[r][q * 4] = v;
    }
#pragma unroll
    for (int i = 0; i < 4; ++i) {
      int flat = t + i * 256;
      int kk = flat >> 4, q = flat & 15;
      float4 v = *(const float4*)(W + (size_t)(k0 + kk) * NH + q * 4);
      *(float4*)&ws[kk][q * 4] = v;
    }
    __syncthreads();
#pragma unroll 8
    for (int kk = 0; kk < 64; ++kk) {
      float a0 = xs[ty * 4 + 0][kk];
      float a1 = xs[ty * 4 + 1][kk];
      float a2 = xs[ty * 4 + 2][kk];
      float a3 = xs[ty * 4 + 3][kk];
      float4 b = *(const float4*)&ws[kk][tx * 4];
      acc[0][0] += a0 * b.x; acc[0][1] += a0 * b.y; acc[0][2] += a0 * b.z; acc[0][3] += a0 * b.w;
      acc[1][0] += a1 * b.x; acc[1][1] += a1 * b.y; acc[1][2] += a1 * b.z; acc[1][3] += a1 * b.w;
      acc[2][0] += a2 * b.x; acc[2][1] += a2 * b.y; acc[2][2] += a2 * b.z; acc[2][3] += a2 * b.w;
      acc[3][0] += a3 * b.x; acc[3][1] += a3 * b.y; acc[3][2] += a3 * b.z; acc[3][3] += a3 * b.w;
    }
    __syncthreads();
  }
#pragma unroll
  for (int i = 0; i < 4; ++i) {
    int row = rowBase + ty * 4 + i;
    if (row < NND)
      *(float4*)(out + (size_t)row * NH + tx * 4) =
          make_float4(acc[i][0], acc[i][1], acc[i][2], acc[i][3]);
  }
}

// ---------------- CSR build ----------------
__global__ __launch_bounds__(256) void hist_k(const int* __restrict__ rows,
                                              int* __restrict__ cnt) {
  int i = blockIdx.x * 256 + threadIdx.x;
  if (i < NE) atomicAdd(&cnt[rows[i]], 1);
}

// phase 1: per-block sums of 1024 counts
__global__ __launch_bounds__(256) void scan_part_k(const int* __restrict__ cnt,
                                                   int* __restrict__ bsum) {
  __shared__ int red[4];
  const int b = blockIdx.x, t = threadIdx.x;
  const int base = b * SCAN_CH + t * 4;
  int s = 0;
#pragma unroll
  for (int i = 0; i < 4; ++i) {
    int j = base + i;
    if (j < NND) s += cnt[j];
  }
#pragma unroll
  for (int off = 32; off; off >>= 1) s += __shfl_down(s, off, 64);
  if ((t & 63) == 0) red[t >> 6] = s;
  __syncthreads();
  if (t == 0) bsum[b] = red[0] + red[1] + red[2] + red[3];
}

// phase 2: single small block, exclusive scan of NSB block sums (in place)
__global__ __launch_bounds__(128) void scan_top_k(int* __restrict__ bsum) {
  __shared__ int sh[128];
  const int t = threadIdx.x;
  int v = (t < NSB) ? bsum[t] : 0;
  sh[t] = v;
  __syncthreads();
#pragma unroll
  for (int off = 1; off < 128; off <<= 1) {
    int u = (t >= off) ? sh[t - off] : 0;
    __syncthreads();
    sh[t] += u;
    __syncthreads();
  }
  if (t < NSB) bsum[t] = sh[t] - v;   // exclusive
}

// phase 3: per-block exclusive scan + offset; write rowptr and cursor
__global__ __launch_bounds__(256) void scan_low_k(const int* __restrict__ cnt,
                                                  const int* __restrict__ bsum,
                                                  int* __restrict__ rowptr,
                                                  int* __restrict__ cursor) {
  __shared__ int part[256];
  const int b = blockIdx.x, t = threadIdx.x;
  const int base = b * SCAN_CH + t * 4;
  int c[4];
  int s = 0;
#pragma unroll
  for (int i = 0; i < 4; ++i) {
    int j = base + i;
    c[i] = (j < NND) ? cnt[j] : 0;
    s += c[i];
  }
  part[t] = s;
  __syncthreads();
#pragma unroll
  for (int off = 1; off < 256; off <<= 1) {
    int u = (t >= off) ? part[t - off] : 0;
    __syncthreads();
    part[t] += u;
    __syncthreads();
  }
  int run = part[t] - s + bsum[b];    // exclusive offset for this thread's 4 elems
#pragma unroll
  for (int i = 0; i < 4; ++i) {
    int j = base + i;
    if (j < NND) {
      rowptr[j] = run;
      cursor[j] = run;
      run += c[i];
    }
  }
  if (b == NSB - 1 && t == 255) rowptr[NND] = NE;
}

__global__ __launch_bounds__(256) void scatter_k(const float* __restrict__ vals,
                                                 const int* __restrict__ rows,
                                                 const int* __restrict__ cols,
                                                 int* __restrict__ cursor,
                                                 int* __restrict__ col_s,
                                                 float* __restrict__ val_s) {
  int i = blockIdx.x * 256 + threadIdx.x;
  if (i >= NE) return;
  int r = rows[i];
  int pos = atomicAdd(&cursor[r], 1);
  col_s[pos] = cols[i];
  val_s[pos] = vals[i];
}

// ---------------- SpMM1 gather: h[r] = relu(sum val*feat[col] + b1), wave per row ----------------
__global__ __launch_bounds__(256) void spmm1g_k(const int* __restrict__ rowptr,
                                                const int* __restrict__ col_s,
                                                const float* __restrict__ val_s,
                                                const float* __restrict__ feat,
                                                const float* __restrict__ b1,
                                                float* __restrict__ h) {
  int wid = threadIdx.x >> 6, lane = threadIdx.x & 63;
  int r = blockIdx.x * 4 + wid;
  if (r >= NND) return;
  int beg = rowptr[r], end = rowptr[r + 1];
  float acc0 = 0.f, acc1 = 0.f;
  int i = beg;
  for (; i + 1 < end; i += 2) {
    acc0 += val_s[i]     * feat[(size_t)col_s[i]     * NH + lane];
    acc1 += val_s[i + 1] * feat[(size_t)col_s[i + 1] * NH + lane];
  }
  if (i < end) acc0 += val_s[i] * feat[(size_t)col_s[i] * NH + lane];
  h[(size_t)r * NH + lane] = fmaxf(acc0 + acc1 + b1[lane], 0.f);
}

// ---------------- GEMM2: support2[N,40] = h[N,64] @ W10[64,40] ----------------
__global__ __launch_bounds__(64) void gemm2_k(const float* __restrict__ h,
                                              const float* __restrict__ W10,
                                              float* __restrict__ out) {
  __shared__ float hs[64][65];
  __shared__ float wl[64][44];
  const int t = threadIdx.x;
  const int rowBase = blockIdx.x * 64;
#pragma unroll
  for (int i = 0; i < 16; ++i) {
    int flat = t + i * 64;
    int r = flat >> 4, q = flat & 15;
    int row = rowBase + r;
    float4 v = make_float4(0.f, 0.f, 0.f, 0.f);
    if (row < NND) v = *(const float4*)(h + (size_t)row * NH + q * 4);
    hs[r][q * 4 + 0] = v.x;
    hs[r][q * 4 + 1] = v.y;
    hs[r][q * 4 + 2] = v.z;
    hs[r][q * 4 + 3] = v.w;
  }
#pragma unroll
  for (int i = 0; i < 10; ++i) {
    int flat = t + i * 64;
    int k = flat / 10, c4 = flat - k * 10;
    float4 v = *(const float4*)(W10 + (size_t)flat * 4);
    *(float4*)&wl[k][c4 * 4] = v;
  }
  __syncthreads();

  float4 acc[10] = {};
#pragma unroll 8
  for (int k = 0; k < 64; ++k) {
    float a = hs[t][k];
#pragma unroll
    for (int c = 0; c < 10; ++c) {
      float4 w = *(const float4*)&wl[k][c * 4];
      acc[c].x += a * w.x;
      acc[c].y += a * w.y;
      acc[c].z += a * w.z;
      acc[c].w += a * w.w;
    }
  }
  int row = rowBase + t;
  if (row < NND) {
#pragma unroll
    for (int c = 0; c < 10; ++c)
      *(float4*)(out + (size_t)row * NC + c * 4) = acc[c];
  }
}

// ---------------- SpMM2 gather + b10 + log_softmax fused, wave per row ----------------
__global__ __launch_bounds__(256) void spmm2g_k(const int* __restrict__ rowptr,
                                                const int* __restrict__ col_s,
                                                const float* __restrict__ val_s,
                                                const float* __restrict__ s2,
                                                const float* __restrict__ b10,
                                                float* __restrict__ out) {
  int wid = threadIdx.x >> 6, lane = threadIdx.x & 63;
  int r = blockIdx.x * 4 + wid;
  if (r >= NND) return;
  int beg = rowptr[r], end = rowptr[r + 1];
  float acc0 = 0.f, acc1 = 0.f;
  if (lane < NC) {
    int i = beg;
    for (; i + 1 < end; i += 2) {
      acc0 += val_s[i]     * s2[(size_t)col_s[i]     * NC + lane];
      acc1 += val_s[i + 1] * s2[(size_t)col_s[i + 1] * NC + lane];
    }
    if (i < end) acc0 += val_s[i] * s2[(size_t)col_s[i] * NC + lane];
  }
  float vv = (lane < NC) ? acc0 + acc1 + b10[lane] : -INFINITY;
  float m = vv;
#pragma unroll
  for (int off = 32; off; off >>= 1) m = fmaxf(m, __shfl_xor(m, off, 64));
  float e = (lane < NC) ? __expf(vv - m) : 0.f;
  float s = e;
#pragma unroll
  for (int off = 32; off; off >>= 1) s += __shfl_xor(s, off, 64);
  if (lane < NC) out[(size_t)r * NC + lane] = vv - m - __logf(s);
}

extern "C" void kernel_launch(void* const* d_in, const int* in_sizes, int n_in,
                              void* d_out, int out_size, void* d_ws, size_t ws_size,
                              hipStream_t stream) {
  const float* x    = (const float*)d_in[0];
  const float* adj  = (const float*)d_in[1];
  const float* W1   = (const float*)d_in[2];
  const float* b1   = (const float*)d_in[3];
  const float* W10  = (const float*)d_in[4];
  const float* b10  = (const float*)d_in[5];
  const int*   erow = (const int*)d_in[6];
  const int*   ecol = (const int*)d_in[7];
  float* out = (float*)d_out;

  float* bufA   = (float*)d_ws;                      // support1 [N,64]; later support2 [N,40]
  float* h      = bufA + (size_t)NND * NH;           // [N,64]
  int*   rowptr = (int*)(h + (size_t)NND * NH);      // [N+1]
  int*   cursor = rowptr + (NND + 1);                // [N] counts -> cursors
  int*   bsum   = cursor + NND;                      // [NSB]
  int*   col_s  = bsum + NSB;                        // [E]
  float* val_s  = (float*)(col_s + NE);              // [E]

  // CSR build
  hipMemsetAsync(cursor, 0, (size_t)NND * sizeof(int), stream);
  hist_k<<<(NE + 255) / 256, 256, 0, stream>>>(erow, cursor);
  scan_part_k<<<NSB, 256, 0, stream>>>(cursor, bsum);
  scan_top_k<<<1, 128, 0, stream>>>(bsum);
  scan_low_k<<<NSB, 256, 0, stream>>>(cursor, bsum, rowptr, cursor);
  scatter_k<<<(NE + 255) / 256, 256, 0, stream>>>(adj, erow, ecol, cursor, col_s, val_s);

  gemm1_k<<<(NND + 63) / 64, 256, 0, stream>>>(x, W1, bufA);
  spmm1g_k<<<(NND + 3) / 4, 256, 0, stream>>>(rowptr, col_s, val_s, bufA, b1, h);
  gemm2_k<<<(NND + 63) / 64, 64, 0, stream>>>(h, W10, bufA);
  spmm2g_k<<<(NND + 3) / 4, 256, 0, stream>>>(rowptr, col_s, val_s, bufA, b10, out);
}

// Round 4
// 423.827 us; speedup vs baseline: 5.9065x; 1.2154x over previous
//
#include <hip/hip_runtime.h>

#define NND 100000
#define NE  1600000
#define NF  512
#define NH  64
#define NC  40

#define SCAN_CH 1024
#define NSB ((NND + SCAN_CH - 1) / SCAN_CH)   // 98 blocks

typedef unsigned short u16;
typedef unsigned int   u32;
typedef __attribute__((ext_vector_type(8))) __bf16 bf16x8;
typedef __attribute__((ext_vector_type(4))) float  f32x4;

__device__ __forceinline__ u16 f2bf(float f) {          // f32 -> bf16 RNE
  u32 u = __builtin_bit_cast(u32, f);
  u += 0x7FFFu + ((u >> 16) & 1u);
  return (u16)(u >> 16);
}
__device__ __forceinline__ u32 pack2(float a, float b) {
  return (u32)f2bf(a) | ((u32)f2bf(b) << 16);
}
__device__ __forceinline__ float bf2f(u16 h) {
  return __builtin_bit_cast(float, (u32)h << 16);
}

// ---------------- W1 [512,64] f32 -> W1T [64,512] bf16 ----------------
__global__ __launch_bounds__(256) void w1t_k(const float* __restrict__ W1,
                                             u16* __restrict__ w1t) {
  int i = blockIdx.x * 256 + threadIdx.x;
  if (i >= NF * NH) return;
  int n = i >> 9, k = i & 511;
  w1t[i] = f2bf(W1[(size_t)k * NH + n]);
}

// ---------------- GEMM1 (bf16 MFMA): s1[N,64] = bf16(x[N,512] @ W1) ----------------
// 128 rows x 64 cols per block, BK=64, 4 waves (32 rows x 64 cols each).
__global__ __launch_bounds__(256) void gemm1_k(const float* __restrict__ x,
                                               const u16* __restrict__ w1t,
                                               u16* __restrict__ out) {
  __shared__ u16 As[2][128][72];   // pad 72: 144B row stride -> conflict-free b128
  __shared__ u16 Bs[2][64][72];
  const int t = threadIdx.x;
  const int w = t >> 6, lane = t & 63;
  const int l15 = lane & 15, l4 = lane >> 4;
  const int rowBase = blockIdx.x * 128;

  f32x4 acc[2][4];
#pragma unroll
  for (int i = 0; i < 2; ++i)
#pragma unroll
    for (int j = 0; j < 4; ++j) acc[i][j] = (f32x4){0.f, 0.f, 0.f, 0.f};

  float4 aR[4][2];
  uint4  bR[2];

  auto issue = [&](int k0) {
#pragma unroll
    for (int i = 0; i < 4; ++i) {
      int c = t + i * 256;               // chunk: row=c>>3, q=c&7 (8 f32 each)
      int row = rowBase + (c >> 3);
      if (row >= NND) row = NND - 1;
      const float4* s = (const float4*)(x + (size_t)row * NF + k0 + (c & 7) * 8);
      aR[i][0] = s[0];
      aR[i][1] = s[1];
    }
#pragma unroll
    for (int i = 0; i < 2; ++i) {
      int c = t + i * 256;               // n=c>>3, q=c&7 (8 bf16 each)
      bR[i] = *(const uint4*)(w1t + (size_t)(c >> 3) * NF + k0 + (c & 7) * 8);
    }
  };
  auto stage = [&](int b) {
#pragma unroll
    for (int i = 0; i < 4; ++i) {
      int c = t + i * 256;
      uint4 v;
      v.x = pack2(aR[i][0].x, aR[i][0].y);
      v.y = pack2(aR[i][0].z, aR[i][0].w);
      v.z = pack2(aR[i][1].x, aR[i][1].y);
      v.w = pack2(aR[i][1].z, aR[i][1].w);
      *(uint4*)&As[b][c >> 3][(c & 7) * 8] = v;
    }
#pragma unroll
    for (int i = 0; i < 2; ++i) {
      int c = t + i * 256;
      *(uint4*)&Bs[b][c >> 3][(c & 7) * 8] = bR[i];
    }
  };

  issue(0);
  for (int it = 0; it < 8; ++it) {
    const int b = it & 1;
    stage(b);                       // waits its own vmcnt, writes LDS
    if (it < 7) issue((it + 1) * 64);   // next tile loads fly under compute
    __syncthreads();                // one barrier per iter (double-buffered)
#pragma unroll
    for (int s = 0; s < 2; ++s) {
      bf16x8 a0 = *(const bf16x8*)&As[b][w * 32 + l15][s * 32 + l4 * 8];
      bf16x8 a1 = *(const bf16x8*)&As[b][w * 32 + 16 + l15][s * 32 + l4 * 8];
#pragma unroll
      for (int ct = 0; ct < 4; ++ct) {
        bf16x8 bb = *(const bf16x8*)&Bs[b][ct * 16 + l15][s * 32 + l4 * 8];
        acc[0][ct] = __builtin_amdgcn_mfma_f32_16x16x32_bf16(a0, bb, acc[0][ct], 0, 0, 0);
        acc[1][ct] = __builtin_amdgcn_mfma_f32_16x16x32_bf16(a1, bb, acc[1][ct], 0, 0, 0);
      }
    }
  }

#pragma unroll
  for (int rt = 0; rt < 2; ++rt)
#pragma unroll
    for (int ct = 0; ct < 4; ++ct)
#pragma unroll
      for (int i = 0; i < 4; ++i) {
        int row = rowBase + w * 32 + rt * 16 + l4 * 4 + i;   // C/D: col=lane&15, row=(lane>>4)*4+reg
        if (row < NND) out[(size_t)row * NH + ct * 16 + l15] = f2bf(acc[rt][ct][i]);
      }
}

// ---------------- CSR build ----------------
__global__ __launch_bounds__(256) void hist_k(const int* __restrict__ rows,
                                              int* __restrict__ cnt) {
  int i = blockIdx.x * 256 + threadIdx.x;
  if (i < NE) atomicAdd(&cnt[rows[i]], 1);
}

__global__ __launch_bounds__(256) void scan_part_k(const int* __restrict__ cnt,
                                                   int* __restrict__ bsum) {
  __shared__ int red[4];
  const int b = blockIdx.x, t = threadIdx.x;
  const int base = b * SCAN_CH + t * 4;
  int s = 0;
#pragma unroll
  for (int i = 0; i < 4; ++i) {
    int j = base + i;
    if (j < NND) s += cnt[j];
  }
#pragma unroll
  for (int off = 32; off; off >>= 1) s += __shfl_down(s, off, 64);
  if ((t & 63) == 0) red[t >> 6] = s;
  __syncthreads();
  if (t == 0) bsum[b] = red[0] + red[1] + red[2] + red[3];
}

__global__ __launch_bounds__(128) void scan_top_k(int* __restrict__ bsum) {
  __shared__ int sh[128];
  const int t = threadIdx.x;
  int v = (t < NSB) ? bsum[t] : 0;
  sh[t] = v;
  __syncthreads();
#pragma unroll
  for (int off = 1; off < 128; off <<= 1) {
    int u = (t >= off) ? sh[t - off] : 0;
    __syncthreads();
    sh[t] += u;
    __syncthreads();
  }
  if (t < NSB) bsum[t] = sh[t] - v;
}

__global__ __launch_bounds__(256) void scan_low_k(const int* __restrict__ cnt,
                                                  const int* __restrict__ bsum,
                                                  int* __restrict__ rowptr,
                                                  int* __restrict__ cursor) {
  __shared__ int part[256];
  const int b = blockIdx.x, t = threadIdx.x;
  const int base = b * SCAN_CH + t * 4;
  int c[4];
  int s = 0;
#pragma unroll
  for (int i = 0; i < 4; ++i) {
    int j = base + i;
    c[i] = (j < NND) ? cnt[j] : 0;
    s += c[i];
  }
  part[t] = s;
  __syncthreads();
#pragma unroll
  for (int off = 1; off < 256; off <<= 1) {
    int u = (t >= off) ? part[t - off] : 0;
    __syncthreads();
    part[t] += u;
    __syncthreads();
  }
  int run = part[t] - s + bsum[b];
#pragma unroll
  for (int i = 0; i < 4; ++i) {
    int j = base + i;
    if (j < NND) {
      rowptr[j] = run;
      cursor[j] = run;
      run += c[i];
    }
  }
  if (b == NSB - 1 && t == 255) rowptr[NND] = NE;
}

__global__ __launch_bounds__(256) void scatter_k(const float* __restrict__ vals,
                                                 const int* __restrict__ rows,
                                                 const int* __restrict__ cols,
                                                 int* __restrict__ cursor,
                                                 int2* __restrict__ edges) {
  int i = blockIdx.x * 256 + threadIdx.x;
  if (i >= NE) return;
  int r = rows[i];
  int pos = atomicAdd(&cursor[r], 1);
  edges[pos] = make_int2(cols[i], __float_as_int(vals[i]));
}

// ---------------- SpMM1 gather (bf16 feat): h = relu(A @ s1 + b1) ----------------
__global__ __launch_bounds__(256) void spmm1g_k(const int* __restrict__ rowptr,
                                                const int2* __restrict__ edges,
                                                const u16* __restrict__ feat,
                                                const float* __restrict__ b1,
                                                float* __restrict__ h) {
  int wid = threadIdx.x >> 6, lane = threadIdx.x & 63;
  int r = blockIdx.x * 4 + wid;
  if (r >= NND) return;
  int beg = rowptr[r], end = rowptr[r + 1];
  float acc = 0.f;
  for (int base = beg; base < end; base += 64) {
    int idx = base + lane;
    int2 e = edges[min(idx, end - 1)];   // coalesced edge load
    int n = min(64, end - base);
    int j = 0;
    for (; j + 1 < n; j += 2) {
      int   c0 = __shfl(e.x, j, 64);
      float v0 = __shfl(__int_as_float(e.y), j, 64);
      int   c1 = __shfl(e.x, j + 1, 64);
      float v1 = __shfl(__int_as_float(e.y), j + 1, 64);
      acc = fmaf(v0, bf2f(feat[(size_t)c0 * NH + lane]), acc);
      acc = fmaf(v1, bf2f(feat[(size_t)c1 * NH + lane]), acc);
    }
    if (j < n) {
      int   c0 = __shfl(e.x, j, 64);
      float v0 = __shfl(__int_as_float(e.y), j, 64);
      acc = fmaf(v0, bf2f(feat[(size_t)c0 * NH + lane]), acc);
    }
  }
  h[(size_t)r * NH + lane] = fmaxf(acc + b1[lane], 0.f);
}

// ---------------- GEMM2: s2[N,40] = bf16(h[N,64] @ W10[64,40]) ----------------
__global__ __launch_bounds__(64) void gemm2_k(const float* __restrict__ h,
                                              const float* __restrict__ W10,
                                              u16* __restrict__ s2out) {
  __shared__ float hs[64][65];
  __shared__ float wl[64][44];
  const int t = threadIdx.x;
  const int rowBase = blockIdx.x * 64;
#pragma unroll
  for (int i = 0; i < 16; ++i) {
    int flat = t + i * 64;
    int r = flat >> 4, q = flat & 15;
    int row = rowBase + r;
    float4 v = make_float4(0.f, 0.f, 0.f, 0.f);
    if (row < NND) v = *(const float4*)(h + (size_t)row * NH + q * 4);
    hs[r][q * 4 + 0] = v.x;
    hs[r][q * 4 + 1] = v.y;
    hs[r][q * 4 + 2] = v.z;
    hs[r][q * 4 + 3] = v.w;
  }
#pragma unroll
  for (int i = 0; i < 10; ++i) {
    int flat = t + i * 64;
    int k = flat / 10, c4 = flat - k * 10;
    float4 v = *(const float4*)(W10 + (size_t)flat * 4);
    *(float4*)&wl[k][c4 * 4] = v;
  }
  __syncthreads();

  float4 acc[10] = {};
#pragma unroll 8
  for (int k = 0; k < 64; ++k) {
    float a = hs[t][k];
#pragma unroll
    for (int c = 0; c < 10; ++c) {
      float4 w = *(const float4*)&wl[k][c * 4];
      acc[c].x += a * w.x;
      acc[c].y += a * w.y;
      acc[c].z += a * w.z;
      acc[c].w += a * w.w;
    }
  }
  int row = rowBase + t;
  if (row < NND) {
#pragma unroll
    for (int c = 0; c < 5; ++c) {
      uint4 o;
      o.x = pack2(acc[c * 2].x,     acc[c * 2].y);
      o.y = pack2(acc[c * 2].z,     acc[c * 2].w);
      o.z = pack2(acc[c * 2 + 1].x, acc[c * 2 + 1].y);
      o.w = pack2(acc[c * 2 + 1].z, acc[c * 2 + 1].w);
      *(uint4*)(s2out + (size_t)row * NC + c * 8) = o;
    }
  }
}

// ---------------- SpMM2 gather (bf16) + b10 + log_softmax ----------------
__global__ __launch_bounds__(256) void spmm2g_k(const int* __restrict__ rowptr,
                                                const int2* __restrict__ edges,
                                                const u16* __restrict__ s2,
                                                const float* __restrict__ b10,
                                                float* __restrict__ out) {
  int wid = threadIdx.x >> 6, lane = threadIdx.x & 63;
  int r = blockIdx.x * 4 + wid;
  if (r >= NND) return;
  int beg = rowptr[r], end = rowptr[r + 1];
  int off = (lane < NC) ? lane : 0;
  float acc = 0.f;
  for (int base = beg; base < end; base += 64) {
    int idx = base + lane;
    int2 e = edges[min(idx, end - 1)];
    int n = min(64, end - base);
    int j = 0;
    for (; j + 1 < n; j += 2) {
      int   c0 = __shfl(e.x, j, 64);
      float v0 = __shfl(__int_as_float(e.y), j, 64);
      int   c1 = __shfl(e.x, j + 1, 64);
      float v1 = __shfl(__int_as_float(e.y), j + 1, 64);
      acc = fmaf(v0, bf2f(s2[(size_t)c0 * NC + off]), acc);
      acc = fmaf(v1, bf2f(s2[(size_t)c1 * NC + off]), acc);
    }
    if (j < n) {
      int   c0 = __shfl(e.x, j, 64);
      float v0 = __shfl(__int_as_float(e.y), j, 64);
      acc = fmaf(v0, bf2f(s2[(size_t)c0 * NC + off]), acc);
    }
  }
  float vv = (lane < NC) ? acc + b10[lane] : -INFINITY;
  float m = vv;
#pragma unroll
  for (int o = 32; o; o >>= 1) m = fmaxf(m, __shfl_xor(m, o, 64));
  float e = (lane < NC) ? __expf(vv - m) : 0.f;
  float s = e;
#pragma unroll
  for (int o = 32; o; o >>= 1) s += __shfl_xor(s, o, 64);
  if (lane < NC) out[(size_t)r * NC + lane] = vv - m - __logf(s);
}

extern "C" void kernel_launch(void* const* d_in, const int* in_sizes, int n_in,
                              void* d_out, int out_size, void* d_ws, size_t ws_size,
                              hipStream_t stream) {
  const float* x    = (const float*)d_in[0];
  const float* adj  = (const float*)d_in[1];
  const float* W1   = (const float*)d_in[2];
  const float* b1   = (const float*)d_in[3];
  const float* W10  = (const float*)d_in[4];
  const float* b10  = (const float*)d_in[5];
  const int*   erow = (const int*)d_in[6];
  const int*   ecol = (const int*)d_in[7];
  float* out = (float*)d_out;

  char* p = (char*)d_ws;
  u16*  s1  = (u16*)p;    p += (size_t)NND * NH * 2;   // 12.8 MB, bf16 support1
  float* h  = (float*)p;  p += (size_t)NND * NH * 4;   // 25.6 MB
  u16*  s2  = (u16*)p;    p += (size_t)NND * NC * 2;   // 8 MB, bf16 support2
  u16*  w1t = (u16*)p;    p += (size_t)NF * NH * 2;    // 64 KB
  int2* edges = (int2*)p; p += (size_t)NE * 8;         // 12.8 MB (8B aligned)
  int* rowptr = (int*)p;  p += (size_t)(NND + 1) * 4;
  int* cursor = (int*)p;  p += (size_t)NND * 4;
  int* bsum   = (int*)p;

  w1t_k<<<(NF * NH + 255) / 256, 256, 0, stream>>>(W1, w1t);

  hipMemsetAsync(cursor, 0, (size_t)NND * sizeof(int), stream);
  hist_k<<<(NE + 255) / 256, 256, 0, stream>>>(erow, cursor);
  scan_part_k<<<NSB, 256, 0, stream>>>(cursor, bsum);
  scan_top_k<<<1, 128, 0, stream>>>(bsum);
  scan_low_k<<<NSB, 256, 0, stream>>>(cursor, bsum, rowptr, cursor);
  scatter_k<<<(NE + 255) / 256, 256, 0, stream>>>(adj, erow, ecol, cursor, edges);

  gemm1_k<<<(NND + 127) / 128, 256, 0, stream>>>(x, w1t, s1);
  spmm1g_k<<<(NND + 3) / 4, 256, 0, stream>>>(rowptr, edges, s1, b1, h);
  gemm2_k<<<(NND + 63) / 64, 64, 0, stream>>>(h, W10, s2);
  spmm2g_k<<<(NND + 3) / 4, 256, 0, stream>>>(rowptr, edges, s2, b10, out);
}